// Round 2
// baseline (445.039 us; speedup 1.0000x reference)
//
#include <hip/hip_runtime.h>
#include <stdint.h>
#include <math.h>

#define BB 256
#define VV 128
#define MM 256
#define TDIM 10
#define HH 1024
#define IN_DIM 35840
#define KSPLIT 16
#define KSLICE 2240   /* IN_DIM/KSPLIT */
#define BK 32
#define NCHUNK 70     /* KSLICE/BK */

using f32x4  = __attribute__((ext_vector_type(4))) float;
using bf16x8 = __attribute__((ext_vector_type(8))) short;

__device__ __forceinline__ unsigned short f2bf(float f) {
    unsigned int u = __float_as_uint(f);
    unsigned int r = (u + 0x7FFFu + ((u >> 16) & 1u)) >> 16;
    return (unsigned short)r;
}

__device__ __forceinline__ void gload_lds16(const void* g, void* l) {
    __builtin_amdgcn_global_load_lds(
        (const __attribute__((address_space(1))) unsigned int*)g,
        (__attribute__((address_space(3))) unsigned int*)l,
        16, 0, 0);
}

// ---------------- K1: build pred_input in bf16 -------------------------
__global__ __launch_bounds__(256)
void k_build(const float* __restrict__ x, const float* __restrict__ memory,
             const int* __restrict__ timings, const float* __restrict__ msurp,
             const float* __restrict__ lastp, short* __restrict__ A)
{
    int b = blockIdx.x, t = threadIdx.x;
    __shared__ int t_s[MM], idx_s[MM], st_s[MM];
    __shared__ float red[MM];
    __shared__ float s_surprise;

    t_s[t] = (t == 0) ? 0 : timings[b*MM + t - 1] + 1;
    red[t] = (t < VV) ? x[b*VV + t] * lastp[b*VV + t] : 0.f;
    __syncthreads();
    for (int s = 128; s > 0; s >>= 1) {
        if (t < s) red[t] += red[t + s];
        __syncthreads();
    }
    if (t == 0) s_surprise = -logf(red[0] + 1e-8f);

    int ti = t_s[t], cnt = 0;
    #pragma unroll 4
    for (int j = 0; j < MM; ++j) {
        int tj = t_s[j];
        cnt += (tj < ti) || (tj == ti && j < t);
    }
    idx_s[cnt] = t;
    st_s[cnt]  = ti;
    __syncthreads();

    float invm = 1.f / ((float)st_s[MM-1] + 1.f);
    short* Ab = A + (size_t)b * IN_DIM;
    {
        int st = st_s[t], src = idx_s[t];
        #pragma unroll
        for (int tt = 0; tt < TDIM; ++tt)
            Ab[32768 + t*TDIM + tt] = (short)f2bf((float)((st >> tt) & 1));
        Ab[35328 + t] = (short)f2bf((float)st * invm);
        float sv = (src == 0) ? s_surprise : msurp[b*MM + src - 1] * 0.99f;
        Ab[35584 + t] = (short)f2bf(sv);
    }
    int half = t >> 7, v = t & (VV-1);
    for (int p = half; p < MM; p += 2) {
        int src = idx_s[p];
        float val = (src == 0) ? x[b*VV + v]
                               : memory[((size_t)b*MM + src - 1)*VV + v];
        Ab[p*VV + v] = (short)f2bf(val);
    }
}

// ---------------- K2: split-K fused bf16 MFMA GEMM ---------------------
// grid (16, 32): x = k-split, y = n-tile of 64 (xt<16 -> W1, else Wg).
// 512 threads = 8 waves; wave (wv&3) covers m-rows, (wv>>2) covers n-half.
// BM=256, BN=64, BK=32.
// Schedule: ONE barrier per chunk.
//   A: 3-stage LDS ring via global_load_lds (R0-proven swizzled layout).
//      At chunk c, DMA(c+2) targets buf[(c+2)%3] = buffer read at c-1,
//      whose reads completed before the c-1/c barrier -> no pre-barrier.
//   W: reg-staged bf16, 2-buffer LDS ring. Regs for c+2 load during chunk
//      c; wregA (=W(c+1)) converts+ds_writes into Ws[(c+1)&1] after MFMA.
//   Sync: s_waitcnt vmcnt(6) lgkmcnt(0) + raw s_barrier. vmcnt(6) = this
//      chunk's own 6 vmem issues -> all older vmem (incl. A-DMA(c+1) and
//      any leftover) drained; never drains to 0 (T4).
// LDS: 3*16KB (A) + 2*4KB (W) = 56KB -> 2 blocks/CU.
__global__ __launch_bounds__(512, 4)
void k_gemm(const short* __restrict__ A, const float* __restrict__ W1,
            const float* __restrict__ Wg, float* __restrict__ P)
{
    int ks = blockIdx.x;          // 0..15
    int xt = blockIdx.y;          // 0..31
    const float* W = (xt < 16) ? W1 : Wg;
    int wcol0 = (xt & 15) * 64;
    int pcol0 = xt * 64;
    int k0 = ks * KSLICE;

    __shared__ bf16x8 As8[3][1024];   // 48 KB
    __shared__ bf16x8 Ws8[2][256];    // 8 KB

    int t = threadIdx.x;
    int l = t & 63, wv = t >> 6;          // wv 0..7
    int r = l & 15, q = l >> 4;
    int wm = wv & 3, nh = wv >> 2;

    // frag slots (chunk-invariant): row R, granule q, swizzle q^((R>>1)&3)
    int aoff[4], boff[2];
    #pragma unroll
    for (int mt = 0; mt < 4; ++mt) {
        int R = wm*64 + mt*16 + r;
        aoff[mt] = R*4 + (q ^ ((R >> 1) & 3));
    }
    #pragma unroll
    for (int nt = 0; nt < 2; ++nt) {
        int R = nh*32 + nt*16 + r;
        boff[nt] = R*4 + (q ^ ((R >> 1) & 3));
    }

    f32x4 acc[4][2];
    #pragma unroll
    for (int mt = 0; mt < 4; ++mt)
        #pragma unroll
        for (int nt = 0; nt < 2; ++nt)
            acc[mt][nt] = (f32x4){0.f, 0.f, 0.f, 0.f};

    // W staging: thread -> (n = l, k-quad = wv): 4 floats, k = kc + wv*4 + j
    int wn = l;
    int wkg = wv >> 1, whalf = wv & 1;    // granule, 8B half
    int wslot16 = (wn*4 + (wkg ^ ((wn >> 1) & 3))) * 16 + whalf * 8;
    const float* wbase = W + (size_t)(k0 + wv*4)*HH + wcol0 + wn;

#define STAGE_A(sbuf, cc) do {                                                \
        int kc_ = k0 + (cc)*BK;                                               \
        {   int G_ = t;                                                       \
            int m_ = G_ >> 2;                                                 \
            int kb_ = (G_ & 3) ^ ((m_ >> 1) & 3);                             \
            gload_lds16(A + (size_t)m_*IN_DIM + kc_ + kb_*8,                  \
                        (void*)(&As8[sbuf][0] + (t & ~63)));                  \
        }                                                                     \
        {   int G_ = t + 512;                                                 \
            int m_ = G_ >> 2;                                                 \
            int kb_ = (G_ & 3) ^ ((m_ >> 1) & 3);                             \
            gload_lds16(A + (size_t)m_*IN_DIM + kc_ + kb_*8,                  \
                        (void*)(&As8[sbuf][0] + (t & ~63) + 512));            \
        }                                                                     \
    } while (0)

#define WCONV(wreg, wdst) do {                                                \
        unsigned int lo_ = (unsigned int)f2bf(wreg[0])                        \
                         | ((unsigned int)f2bf(wreg[1]) << 16);               \
        unsigned int hi_ = (unsigned int)f2bf(wreg[2])                        \
                         | ((unsigned int)f2bf(wreg[3]) << 16);               \
        unsigned int* d_ = (unsigned int*)((char*)&Ws8[wdst][0] + wslot16);   \
        d_[0] = lo_; d_[1] = hi_;                                             \
    } while (0)

#define WLOAD(wreg, cc) do {                                                  \
        const float* wp_ = wbase + (size_t)(cc)*BK*HH;                        \
        _Pragma("unroll")                                                     \
        for (int j_ = 0; j_ < 4; ++j_) wreg[j_] = wp_[(size_t)j_*HH];         \
    } while (0)

    float wA[4], wB[4], w0[4];

    // ---- prologue: W(0)->Ws[0]; A(0),A(1) dma; W(1)->wA; full drain ----
    WLOAD(w0, 0);
    STAGE_A(0, 0);
    STAGE_A(1, 1);
    WLOAD(wA, 1);
    WCONV(w0, 0);
    asm volatile("s_waitcnt vmcnt(0) lgkmcnt(0)" ::: "memory");
    __builtin_amdgcn_s_barrier();

    // chunk body: reads As8[c%3], Ws8[c&1]; issues DMA(c+2), WLOAD(c+2);
    // converts W(c+1) into Ws8[(c+1)&1]; one counted-wait barrier.
#define CHUNK(c, WCUR, WNXT) do {                                             \
        int pb_ = (c) % 3;                                                    \
        int wrd_ = (c) & 1;                                                   \
        int cN_ = ((c) + 2 < NCHUNK) ? (c) + 2 : NCHUNK - 1;                  \
        STAGE_A(((c) + 2) % 3, cN_);                                          \
        WLOAD(WNXT, cN_);                                                     \
        {                                                                     \
            bf16x8 af_[4], bf_[2];                                            \
            _Pragma("unroll")                                                 \
            for (int mt = 0; mt < 4; ++mt) af_[mt] = As8[pb_][aoff[mt]];      \
            _Pragma("unroll")                                                 \
            for (int nt = 0; nt < 2; ++nt) bf_[nt] = Ws8[wrd_][boff[nt]];     \
            _Pragma("unroll")                                                 \
            for (int mt = 0; mt < 4; ++mt)                                    \
                _Pragma("unroll")                                             \
                for (int nt = 0; nt < 2; ++nt)                                \
                    acc[mt][nt] = __builtin_amdgcn_mfma_f32_16x16x32_bf16(    \
                        af_[mt], bf_[nt], acc[mt][nt], 0, 0, 0);              \
        }                                                                     \
        WCONV(WCUR, wrd_ ^ 1);                                                \
        asm volatile("s_waitcnt vmcnt(6) lgkmcnt(0)" ::: "memory");           \
        __builtin_amdgcn_s_barrier();                                         \
    } while (0)

    #pragma unroll 1
    for (int c = 0; c < NCHUNK; c += 2) {
        CHUNK(c,     wA, wB);
        CHUNK(c + 1, wB, wA);
    }
#undef CHUNK
#undef WLOAD
#undef WCONV
#undef STAGE_A

    // epilogue: partials P[ks][m][2048]
    #pragma unroll
    for (int mt = 0; mt < 4; ++mt)
        #pragma unroll
        for (int nt = 0; nt < 2; ++nt)
            #pragma unroll
            for (int rg = 0; rg < 4; ++rg) {
                int m = wm*64 + mt*16 + q*4 + rg;
                int n = pcol0 + nh*32 + nt*16 + r;
                P[((size_t)ks*BB + m)*2048 + n] = acc[mt][nt][rg];
            }
}

// ---------------- K3: split-K reduce + bias + sigmoid gate (float4) ----
__global__ __launch_bounds__(256)
void k_reduce(const float* __restrict__ P, const float* __restrict__ b1,
              const float* __restrict__ bg, float* __restrict__ h)
{
    int b = blockIdx.x, t = threadIdx.x;       // t indexes 4-wide j groups
    const f32x4* P4 = (const f32x4*)P;
    f32x4 p1 = ((const f32x4*)b1)[t];
    f32x4 pg = ((const f32x4*)bg)[t];
    #pragma unroll
    for (int ks = 0; ks < KSPLIT; ++ks) {
        size_t base = ((size_t)ks*BB + b) * 512;   // 2048 floats / 4
        p1 += P4[base + t];
        pg += P4[base + 256 + t];
    }
    f32x4 o;
    #pragma unroll
    for (int j = 0; j < 4; ++j)
        o[j] = p1[j] / (1.f + expf(-pg[j]));
    ((f32x4*)h)[(size_t)b*256 + t] = o;
}

// ---------------- K4: h @ W2 + b2 (one batch row per block) ------------
__global__ __launch_bounds__(256)
void k_out(const float* __restrict__ h, const float* __restrict__ W2,
           const float* __restrict__ b2, float* __restrict__ out)
{
    int b = blockIdx.x, t = threadIdx.x;
    int v = t & 127, kh = t >> 7;          // k-split by 2
    const float* hb = h + (size_t)b*HH + kh*512;
    const float* wp = W2 + (size_t)kh*512*VV + v;
    float acc = 0.f;
    #pragma unroll 8
    for (int k = 0; k < 512; ++k)
        acc += hb[k] * wp[(size_t)k*VV];
    __shared__ float s[256];
    s[t] = acc;
    __syncthreads();
    if (t < 128)
        out[(size_t)b*VV + v] = s[t] + s[t + 128] + b2[v];
}

extern "C" void kernel_launch(void* const* d_in, const int* in_sizes, int n_in,
                              void* d_out, int out_size, void* d_ws, size_t ws_size,
                              hipStream_t stream)
{
    const float* x    = (const float*)d_in[0];
    const float* mem  = (const float*)d_in[1];
    const int*   tim  = (const int*)d_in[2];
    const float* msur = (const float*)d_in[3];
    const float* lp   = (const float*)d_in[4];
    const float* W1   = (const float*)d_in[5];
    const float* b1   = (const float*)d_in[6];
    const float* Wg   = (const float*)d_in[7];
    const float* bg   = (const float*)d_in[8];
    const float* W2   = (const float*)d_in[9];
    const float* b2   = (const float*)d_in[10];
    float* out = (float*)d_out;

    // ws layout: A bf16 [256][35840] | P fp32 [16][256][2048] | h fp32 [256][1024]
    short* A = (short*)d_ws;
    float* P = (float*)((char*)d_ws + 18350080);
    float* h = (float*)((char*)d_ws + 51904512);

    k_build <<<256, 256, 0, stream>>>(x, mem, tim, msur, lp, A);
    k_gemm  <<<dim3(KSPLIT, 32), 512, 0, stream>>>(A, W1, Wg, P);
    k_reduce<<<256, 256, 0, stream>>>(P, b1, bg, h);
    k_out   <<<256, 256, 0, stream>>>(h, W2, b2, out);
}

// Round 3
// 402.988 us; speedup vs baseline: 1.1043x; 1.1043x over previous
//
#include <hip/hip_runtime.h>
#include <stdint.h>
#include <math.h>

#define BB 256
#define VV 128
#define MM 256
#define TDIM 10
#define HH 1024
#define IN_DIM 35840
#define KSPLIT 16
#define KSLICE 2240   /* IN_DIM/KSPLIT */
#define BK 32
#define NCHUNK 70     /* KSLICE/BK */

using f32x4  = __attribute__((ext_vector_type(4))) float;
using bf16x8 = __attribute__((ext_vector_type(8))) short;

__device__ __forceinline__ unsigned short f2bf(float f) {
    unsigned int u = __float_as_uint(f);
    unsigned int r = (u + 0x7FFFu + ((u >> 16) & 1u)) >> 16;
    return (unsigned short)r;
}

__device__ __forceinline__ void gload_lds16(const void* g, void* l) {
    __builtin_amdgcn_global_load_lds(
        (const __attribute__((address_space(1))) unsigned int*)g,
        (__attribute__((address_space(3))) unsigned int*)l,
        16, 0, 0);
}

// ---------------- K1: build pred_input in bf16 -------------------------
// 512 threads (8 waves, 2/SIMD). Gather loop: 4-way p-split, 64 iters,
// unroll 8, clamped UNCONDITIONAL loads so 8 loads pipeline per batch.
__global__ __launch_bounds__(512)
void k_build(const float* __restrict__ x, const float* __restrict__ memory,
             const int* __restrict__ timings, const float* __restrict__ msurp,
             const float* __restrict__ lastp, short* __restrict__ A)
{
    int b = blockIdx.x, t = threadIdx.x;
    __shared__ int t_s[MM], idx_s[MM], st_s[MM];
    __shared__ float s_surprise;

    if (t < MM) t_s[t] = (t == 0) ? 0 : timings[b*MM + t - 1] + 1;
    if (t < 64) {
        float v = x[b*VV + t] * lastp[b*VV + t]
                + x[b*VV + t + 64] * lastp[b*VV + t + 64];
        #pragma unroll
        for (int off = 32; off > 0; off >>= 1)
            v += __shfl_down(v, off, 64);
        if (t == 0) s_surprise = -logf(v + 1e-8f);
    }
    __syncthreads();

    if (t < MM) {
        int ti = t_s[t], cnt = 0;
        #pragma unroll 4
        for (int j = 0; j < MM; ++j) {
            int tj = t_s[j];
            cnt += (tj < ti) || (tj == ti && j < t);
        }
        idx_s[cnt] = t;
        st_s[cnt]  = ti;
    }
    __syncthreads();

    short* Ab = A + (size_t)b * IN_DIM;
    if (t < MM) {
        float invm = 1.f / ((float)st_s[MM-1] + 1.f);
        int st = st_s[t], src = idx_s[t];
        #pragma unroll
        for (int tt = 0; tt < TDIM; ++tt)
            Ab[32768 + t*TDIM + tt] = (short)f2bf((float)((st >> tt) & 1));
        Ab[35328 + t] = (short)f2bf((float)st * invm);
        float sv = (src == 0) ? s_surprise : msurp[b*MM + src - 1] * 0.99f;
        Ab[35584 + t] = (short)f2bf(sv);
    }

    // gather memory rows -> A (sorted order). quarter q4 handles p = q4+4i.
    int q4 = t >> 7, v = t & (VV-1);
    float xv = x[b*VV + v];
    #pragma unroll 8
    for (int p = q4; p < MM; p += 4) {
        int src = idx_s[p];
        int row = (src == 0) ? 0 : src - 1;           // clamped, always valid
        float mv = memory[((size_t)b*MM + row)*VV + v];
        float val = (src == 0) ? xv : mv;
        Ab[p*VV + v] = (short)f2bf(val);
    }
}

// ---------------- K2: split-K fused bf16 MFMA GEMM, 3-stage ring -------
// (R1 version verbatim -- best measured 133.4 us, zero bank conflicts.)
__global__ __launch_bounds__(512, 4)
void k_gemm(const short* __restrict__ A, const float* __restrict__ W1,
            const float* __restrict__ Wg, float* __restrict__ P)
{
    int ks = blockIdx.x;          // 0..15
    int xt = blockIdx.y;          // 0..31
    const float* W = (xt < 16) ? W1 : Wg;
    int wcol0 = (xt & 15) * 64;
    int pcol0 = xt * 64;
    int k0 = ks * KSLICE;

    __shared__ bf16x8 As8[3][1024];   // 48 KB
    __shared__ float  Wl[3][2048];    // 24 KB

    int t = threadIdx.x;
    int l = t & 63, wv = t >> 6;          // wv 0..7
    int r = l & 15, q = l >> 4;
    int wm = wv & 3, nh = wv >> 2;

    // A frag slots (chunk-invariant): row R, granule q, swizzle q^((R>>1)&3)
    int aoff[4];
    #pragma unroll
    for (int mt = 0; mt < 4; ++mt) {
        int R = wm*64 + mt*16 + r;
        aoff[mt] = R*4 + (q ^ ((R >> 1) & 3));
    }
    // W frag columns, pre-XORed with this lane's k-granule swizzle
    int ncol[2];
    #pragma unroll
    for (int nt = 0; nt < 2; ++nt) {
        int n = nh*32 + nt*16 + r;
        ncol[nt] = n ^ (q << 4);
    }

    f32x4 acc[4][2];
    #pragma unroll
    for (int mt = 0; mt < 4; ++mt)
        #pragma unroll
        for (int nt = 0; nt < 2; ++nt)
            acc[mt][nt] = (f32x4){0.f, 0.f, 0.f, 0.f};

    // W-dma per-thread params: thread t stages k-row (t>>4), 4 floats at
    // swizzled column ((t&15)*4) ^ ((krow>>3)<<4). LDS dest is linear t*16B.
    int wkk = t >> 4;
    int wnF = ((t & 15) * 4) ^ (((wkk >> 3) & 3) << 4);

#define STAGE(sbuf, cc) do {                                                  \
        int kc_ = k0 + (cc)*BK;                                               \
        {   int G_ = t;                                                       \
            int m_ = G_ >> 2;                                                 \
            int kb_ = (G_ & 3) ^ ((m_ >> 1) & 3);                             \
            gload_lds16(A + (size_t)m_*IN_DIM + kc_ + kb_*8,                  \
                        (char*)&As8[sbuf][0] + (size_t)(t & ~63)*16);         \
        }                                                                     \
        {   int G_ = t + 512;                                                 \
            int m_ = G_ >> 2;                                                 \
            int kb_ = (G_ & 3) ^ ((m_ >> 1) & 3);                             \
            gload_lds16(A + (size_t)m_*IN_DIM + kc_ + kb_*8,                  \
                        (char*)&As8[sbuf][0] + (size_t)((t & ~63) + 512)*16); \
        }                                                                     \
        gload_lds16(W + (size_t)(kc_ + wkk)*HH + wcol0 + wnF,                 \
                    (char*)&Wl[sbuf][0] + (size_t)(t & ~63)*16);              \
    } while (0)

    // ---- prologue: fill 3 stages, wait for stage 0 only (vmcnt 6) ----
    STAGE(0, 0);
    STAGE(1, 1);
    STAGE(2, 2);
    asm volatile("s_waitcnt vmcnt(6)" ::: "memory");
    __builtin_amdgcn_s_barrier();

    for (int c = 0; c < NCHUNK; ++c) {
        int buf = c % 3;

        // frag reads from stage c
        bf16x8 af[4], bfr[2];
        #pragma unroll
        for (int mt = 0; mt < 4; ++mt) af[mt] = As8[buf][aoff[mt]];
        #pragma unroll
        for (int nt = 0; nt < 2; ++nt) {
            const float* wb = &Wl[buf][ncol[nt]];
            bf16x8 bb;
            #pragma unroll
            for (int j = 0; j < 8; ++j)
                bb[j] = (short)f2bf(wb[(q*8 + j)*64]);
            bfr[nt] = bb;
        }
        #pragma unroll
        for (int mt = 0; mt < 4; ++mt)
            #pragma unroll
            for (int nt = 0; nt < 2; ++nt)
                acc[mt][nt] = __builtin_amdgcn_mfma_f32_16x16x32_bf16(
                    af[mt], bfr[nt], acc[mt][nt], 0, 0, 0);

        // all waves done reading stage c -> safe to overwrite its buffer
        __builtin_amdgcn_s_barrier();
        {
            int cn = (c + 3 < NCHUNK) ? c + 3 : NCHUNK - 1;  // clamped dup
            STAGE(buf, cn);                                   // into buf[(c+3)%3]
        }
        // 2 stages (6 instr) stay in flight; guarantees stage c+1 landed
        asm volatile("s_waitcnt vmcnt(6)" ::: "memory");
        __builtin_amdgcn_s_barrier();
    }
#undef STAGE

    // epilogue: partials P[ks][m][2048]
    #pragma unroll
    for (int mt = 0; mt < 4; ++mt)
        #pragma unroll
        for (int nt = 0; nt < 2; ++nt)
            #pragma unroll
            for (int rg = 0; rg < 4; ++rg) {
                int m = wm*64 + mt*16 + q*4 + rg;
                int n = pcol0 + nh*32 + nt*16 + r;
                P[((size_t)ks*BB + m)*2048 + n] = acc[mt][nt][rg];
            }
}

// ---------------- K3: fused split-K reduce + gate + (h @ W2 + b2) ------
// 512 threads, one block per batch row. Phase 1: each thread sums one
// f32x4 quad of P over 16 k-splits (16 independent loads in flight).
// Phase 2: gate -> h in LDS. Phase 3: W2 matvec with 4-way k-split.
__global__ __launch_bounds__(512)
void k_tail(const float* __restrict__ P, const float* __restrict__ b1,
            const float* __restrict__ bg, const float* __restrict__ W2,
            const float* __restrict__ b2, float* __restrict__ out)
{
    int b = blockIdx.x, t = threadIdx.x;
    __shared__ f32x4 part[512];          // 8 KB
    __shared__ float hs[HH];             // 4 KB
    __shared__ float s2[512];            // 2 KB

    const f32x4* P4 = (const f32x4*)P;
    f32x4 s = (f32x4){0.f, 0.f, 0.f, 0.f};
    #pragma unroll
    for (int ks = 0; ks < KSPLIT; ++ks)
        s += P4[((size_t)ks*BB + b)*512 + t];
    part[t] = s;
    __syncthreads();

    if (t < 256) {
        f32x4 p1 = part[t]       + ((const f32x4*)b1)[t];
        f32x4 pg = part[t + 256] + ((const f32x4*)bg)[t];
        f32x4 o;
        #pragma unroll
        for (int j = 0; j < 4; ++j)
            o[j] = p1[j] / (1.f + expf(-pg[j]));
        ((f32x4*)hs)[t] = o;
    }
    __syncthreads();

    int v = t & 127, kh = t >> 7;        // 4-way k-split, 256 k each
    const float* wp = W2 + (size_t)kh*256*VV + v;
    const float* hk = hs + kh*256;
    float acc = 0.f;
    #pragma unroll 8
    for (int k = 0; k < 256; ++k)
        acc += hk[k] * wp[(size_t)k*VV];
    s2[t] = acc;
    __syncthreads();
    if (t < 128)
        out[(size_t)b*VV + v] = s2[t] + s2[t+128] + s2[t+256] + s2[t+384] + b2[v];
}

extern "C" void kernel_launch(void* const* d_in, const int* in_sizes, int n_in,
                              void* d_out, int out_size, void* d_ws, size_t ws_size,
                              hipStream_t stream)
{
    const float* x    = (const float*)d_in[0];
    const float* mem  = (const float*)d_in[1];
    const int*   tim  = (const int*)d_in[2];
    const float* msur = (const float*)d_in[3];
    const float* lp   = (const float*)d_in[4];
    const float* W1   = (const float*)d_in[5];
    const float* b1   = (const float*)d_in[6];
    const float* Wg   = (const float*)d_in[7];
    const float* bg   = (const float*)d_in[8];
    const float* W2   = (const float*)d_in[9];
    const float* b2   = (const float*)d_in[10];
    float* out = (float*)d_out;

    // ws layout: A bf16 [256][35840] | P fp32 [16][256][2048]
    short* A = (short*)d_ws;
    float* P = (float*)((char*)d_ws + 18350080);

    k_build <<<256, 512, 0, stream>>>(x, mem, tim, msur, lp, A);
    k_gemm  <<<dim3(KSPLIT, 32), 512, 0, stream>>>(A, W1, Wg, P);
    k_tail  <<<256, 512, 0, stream>>>(P, b1, bg, W2, b2, out);
}